// Round 24
// baseline (154.244 us; speedup 1.0000x reference)
//
#include <hip/hip_runtime.h>
#include <stdint.h>

#define N_NODES 8192
#define IN_FEAT 512
#define OUT_FEAT 256
#define LOG2E 1.4426950408889634f

typedef __bf16 b16x8 __attribute__((ext_vector_type(8)));
typedef unsigned short u16x8v __attribute__((ext_vector_type(8)));
typedef float f32x4 __attribute__((ext_vector_type(4)));
typedef float f32x16 __attribute__((ext_vector_type(16)));

static __device__ __forceinline__ unsigned short f2bf(float f) {
    union { float f; uint32_t u; } v; v.f = f;
    uint32_t r = v.u + 0x7FFFu + ((v.u >> 16) & 1u);
    return (unsigned short)(r >> 16);
}
static __device__ __forceinline__ float bf2f(unsigned short s) {
    union { uint32_t u; float f; } v; v.u = ((uint32_t)s) << 16;
    return v.f;
}

// K0: Wt[c][k] = bf16(W[k][c])  (256 x 512)
__global__ __launch_bounds__(256) void k0_transpose_w(const float* __restrict__ W,
                                                      unsigned short* __restrict__ Wt) {
    int tid = blockIdx.x * 256 + threadIdx.x;
    int c = tid & (OUT_FEAT - 1);
    int k = tid >> 8;
    Wt[(size_t)c * IN_FEAT + k] = f2bf(W[(size_t)k * OUT_FEAT + c]);
}

// K1: h = X @ W via bf16 MFMA (16x16x32 internally). Writes hTf32 in the
// B-fragment order of mfma_f32_32x32x16_bf16 (verified R16).
__global__ __launch_bounds__(256) void k1_hgemm(const float* __restrict__ input,
                                                const unsigned short* __restrict__ Wt,
                                                const float* __restrict__ a_vec,
                                                unsigned short* __restrict__ hTf32,
                                                float* __restrict__ s1_raw,
                                                float* __restrict__ s2_raw) {
    int tid = threadIdx.x;
    int lane = tid & 63;
    int c = lane & 15, g = lane >> 4;
    int r0 = blockIdx.x * 64 + (tid >> 6) * 16;
    f32x4 acc[16];
#pragma unroll
    for (int t = 0; t < 16; ++t) acc[t] = (f32x4){0.f, 0.f, 0.f, 0.f};
    const float* arow = input + (size_t)(r0 + c) * IN_FEAT;
#pragma unroll 1
    for (int kk = 0; kk < IN_FEAT / 32; ++kk) {
        int kb = kk * 32 + 8 * g;
        float4 x0 = *(const float4*)(arow + kb);
        float4 x1 = *(const float4*)(arow + kb + 4);
        u16x8v au;
        au[0] = f2bf(x0.x); au[1] = f2bf(x0.y); au[2] = f2bf(x0.z); au[3] = f2bf(x0.w);
        au[4] = f2bf(x1.x); au[5] = f2bf(x1.y); au[6] = f2bf(x1.z); au[7] = f2bf(x1.w);
        b16x8 af = __builtin_bit_cast(b16x8, au);
#pragma unroll
        for (int t = 0; t < 16; ++t) {
            b16x8 bf = __builtin_bit_cast(b16x8,
                *(const u16x8v*)(Wt + (size_t)(16 * t + c) * IN_FEAT + kb));
            acc[t] = __builtin_amdgcn_mfma_f32_16x16x32_bf16(af, bf, acc[t], 0, 0, 0);
        }
    }
    float a1v[16], a2v[16];
#pragma unroll
    for (int t = 0; t < 16; ++t) {
        a1v[t] = a_vec[16 * t + c];
        a2v[t] = a_vec[OUT_FEAT + 16 * t + c];
    }
#pragma unroll
    for (int r = 0; r < 4; ++r) {
        float s1p = 0.f, s2p = 0.f;
#pragma unroll
        for (int t = 0; t < 16; ++t) { s1p += acc[t][r] * a1v[t]; s2p += acc[t][r] * a2v[t]; }
#pragma unroll
        for (int m = 1; m <= 8; m <<= 1) { s1p += __shfl_xor(s1p, m); s2p += __shfl_xor(s2p, m); }
        if (c == 0) {
            int row = r0 + 4 * g + r;
            s1_raw[row] = s1p;
            s2_raw[row] = s2p;
        }
    }
    // store in 32x32 B-frag order
    int chunk16 = r0 >> 4;
    int lane_base = c + 32 * (g >> 1);
    int e0 = 4 * (g & 1);
#pragma unroll
    for (int t = 0; t < 16; ++t) {
        ushort4 pk;
        pk.x = f2bf(acc[t][0]); pk.y = f2bf(acc[t][1]);
        pk.z = f2bf(acc[t][2]); pk.w = f2bf(acc[t][3]);
        int lane_t = 16 * (t & 1) + lane_base;
        *(ushort4*)(hTf32 + ((size_t)(chunk16 * 8 + (t >> 1)) * 64 + lane_t) * 8 + e0) = pk;
    }
}

// K2: factored-exp constants.
__global__ __launch_bounds__(256) void k2_prep(const float* __restrict__ s1_raw,
                                               const float* __restrict__ s2_raw,
                                               float* __restrict__ e12,
                                               float2* __restrict__ row2) {
    __shared__ float red[256];
    int tid = threadIdx.x;
    float m = -3.0e38f;
    for (int j = tid; j < N_NODES; j += 256) m = fmaxf(m, s2_raw[j]);
    red[tid] = m;
    __syncthreads();
    for (int s = 128; s > 0; s >>= 1) {
        if (tid < s) red[tid] = fmaxf(red[tid], red[tid + s]);
        __syncthreads();
    }
    float M2 = red[0];
    int i = blockIdx.x * 256 + tid;
    float s1 = s1_raw[i];
    float u = s1 + M2;
    float mi = fmaxf(u, 0.2f * u);                 // per-row upper bound on e
    row2[i] = make_float2(__builtin_amdgcn_exp2f((s1 - mi) * LOG2E),
                          __builtin_amdgcn_exp2f((0.2f * s1 - mi) * LOG2E));
    float s2 = s2_raw[i];
    e12[2 * i]     = __builtin_amdgcn_exp2f(s2 * LOG2E);
    e12[2 * i + 1] = __builtin_amdgcn_exp2f(0.2f * s2 * LOG2E);
}

// K3 v23: fused pack+flash-GAT, DEPTH-2 adj register pipeline, jq=4.
// Grid 1024 = 256 rowgroups (32 rows) x 4 jq (j-quarters, 2048 js). Block =
// 256 = 4 cq waves, wave owns 2 col-tiles. 16 groups/block (group = 8
// chunk16s = 128 js; same staging mapping as R23). Iteration kc8:
//   A) issue adj loads for group kc8+2 -> vb
//   B) produce 2 af slots from lmask[cur]
//   barrier
//   C) consume 8 slots (b-frags + 16 MFMA)
//   D) pack va (group kc8+1, issued LAST iteration: ~1.7 phases of latency
//      cover > HBM ~900cy) -> lmask[cur^1]; va = vb
//   barrier
// jq=4 halves partial traffic (poutb 16 MB) and k4 work vs R23's jq=8.
__global__ __launch_bounds__(256, 4) void k3_flash(const int* __restrict__ adj,
                                                   const unsigned short* __restrict__ hTf32,
                                                   const float* __restrict__ e12g,
                                                   const float2* __restrict__ row2,
                                                   unsigned short* __restrict__ poutb,
                                                   float* __restrict__ rowpart) {
    __shared__ __align__(16) float le12[4096];               // 16 KB (quarter)
    __shared__ __align__(16) unsigned short laf[8][512];     // 8 KB af slots
    __shared__ __align__(16) uint32_t lmask[2][32][4];       // 1 KB dbuf masks
    __shared__ float lsum[4][64];                            // 1 KB

    int tid = threadIdx.x;
    int cq = tid >> 6, lane = tid & 63;
    int lr = lane & 31, lo = lane >> 5;
    int jq = blockIdx.x & 3;
    int rg = blockIdx.x >> 2;
    int rowbase = rg * 32;

    // adj staging mapping: thread t -> row t>>3, j-block (t&7)*16 within group
    int srow = tid >> 3;
    int sjb = tid & 7;
    const int* adjbase = adj + (size_t)(rowbase + srow) * N_NODES + jq * 2048 + sjb * 16;

    // ---- prologue: stage e12 quarter (16 floats/thread) ----
#pragma unroll
    for (int q = 0; q < 4; ++q) {
        *(float4*)&le12[tid * 16 + q * 4] =
            *(const float4*)(e12g + (size_t)jq * 4096 + tid * 16 + q * 4);
    }

#define PACK16(BUF, V)                                                                   \
    {                                                                                    \
        unsigned pb = 0;                                                                 \
        _Pragma("unroll")                                                                \
        for (int k = 0; k < 4; ++k) {                                                    \
            pb |= ((unsigned)((V)[k].x != 0) << (4 * k))                                 \
                | ((unsigned)((V)[k].y != 0) << (4 * k + 1))                             \
                | ((unsigned)((V)[k].z != 0) << (4 * k + 2))                             \
                | ((unsigned)((V)[k].w != 0) << (4 * k + 3));                            \
        }                                                                                \
        *(unsigned short*)((char*)&lmask[BUF][srow][0] + sjb * 2) = (unsigned short)pb;  \
    }

    {   // synchronous pack of group 0 into lmask[0]
        int4 v[4];
#pragma unroll
        for (int k = 0; k < 4; ++k) v[k] = *(const int4*)(adjbase + 4 * k);
        PACK16(0, v)
    }
    // in-flight regs for group 1 (packed at D of kc8=0)
    int4 va0 = *(const int4*)(adjbase + 128);
    int4 va1 = *(const int4*)(adjbase + 132);
    int4 va2 = *(const int4*)(adjbase + 136);
    int4 va3 = *(const int4*)(adjbase + 140);
    float2 rc = row2[rowbase + lr];
    float E1r = rc.x, E2r = rc.y;
    __syncthreads();

    f32x16 acc0 = {0}, acc1 = {0};
    float lacc = 0.f;

#pragma unroll 1
    for (int kc8 = 0; kc8 < 16; ++kc8) {
        int cur = kc8 & 1;

        // A) issue adj loads for group kc8+2 (packed NEXT iteration)
        int4 vb0, vb1, vb2, vb3;
        if (kc8 < 14) {
            vb0 = *(const int4*)(adjbase + (kc8 + 2) * 128);
            vb1 = *(const int4*)(adjbase + (kc8 + 2) * 128 + 4);
            vb2 = *(const int4*)(adjbase + (kc8 + 2) * 128 + 8);
            vb3 = *(const int4*)(adjbase + (kc8 + 2) * 128 + 12);
        }

        // B) produce 2 af slots (chunks kc8*8+cq, kc8*8+4+cq) from lmask[cur]
        int4 mq = *(const int4*)&lmask[cur][lr][0];
        uint32_t md[4] = {(uint32_t)mq.x, (uint32_t)mq.y, (uint32_t)mq.z, (uint32_t)mq.w};
#pragma unroll
        for (int hh = 0; hh < 2; ++hh) {
            int sl = hh * 4 + cq;
            int kc = kc8 * 8 + sl;                 // chunk16 in quarter (0..127)
            float ev[16];
#pragma unroll
            for (int q = 0; q < 4; ++q)
                *(f32x4*)&ev[q * 4] = *(const f32x4*)&le12[(kc * 16 + 8 * lo) * 2 + q * 4];
            uint32_t mb = (md[sl >> 1] >> (16 * (sl & 1) + 8 * lo)) & 0xFFu;
            b16x8 af;
#pragma unroll
            for (int e = 0; e < 8; ++e) {
                float q0 = fmaxf(E1r * ev[2 * e], E2r * ev[2 * e + 1]);
                float p = (mb & (1u << e)) ? q0 : 0.f;
                lacc += p;
                af[e] = (__bf16)p;
            }
            *(u16x8v*)&laf[sl][lane * 8] = __builtin_bit_cast(u16x8v, af);
        }
        __syncthreads();

        // C) consume 8 slots with this wave's 2 col-tiles
        int gchunk0 = jq * 128 + kc8 * 8;          // global chunk16
#pragma unroll
        for (int s = 0; s < 8; ++s) {
            const unsigned short* tb =
                hTf32 + ((size_t)((gchunk0 + s) * 8 + 2 * cq) * 64 + lane) * 8;
            b16x8 bf0 = __builtin_bit_cast(b16x8, *(const u16x8v*)(tb));
            b16x8 bf1 = __builtin_bit_cast(b16x8, *(const u16x8v*)(tb + 512));
            b16x8 afs = __builtin_bit_cast(b16x8, *(const u16x8v*)&laf[s][lane * 8]);
            acc0 = __builtin_amdgcn_mfma_f32_32x32x16_bf16(afs, bf0, acc0, 0, 0, 0);
            acc1 = __builtin_amdgcn_mfma_f32_32x32x16_bf16(afs, bf1, acc1, 0, 0, 0);
        }

        // D) pack group kc8+1 (regs from last iteration; counted vmcnt) ; rotate
        if (kc8 < 15) {
            int4 va[4] = {va0, va1, va2, va3};
            PACK16(cur ^ 1, va)
        }
        va0 = vb0; va1 = vb1; va2 = vb2; va3 = vb3;
        __syncthreads();                           // laf + lmask[cur^1] ready
    }
#undef PACK16

    // row sums: wave cq produced chunks ≡ {cq, cq+4} (mod 8); merge via LDS
    lsum[cq][lane] = lacc;
    __syncthreads();
    if (cq == 0) {
        float l = lsum[0][lane] + lsum[1][lane] + lsum[2][lane] + lsum[3][lane];
        float ltot = l + __shfl_xor(l, 32);
        if (lo == 0) rowpart[jq * N_NODES + rowbase + lr] = ltot;
    }

    // C layout (32x32): col = lane&31, row = (reg&3) + 8*(reg>>2) + 4*(lane>>5)
#pragma unroll
    for (int reg = 0; reg < 16; ++reg) {
        int row = (reg & 3) + 8 * (reg >> 2) + 4 * lo;
        size_t base = ((size_t)jq * N_NODES + rowbase + row) * OUT_FEAT + cq * 64 + lr;
        poutb[base] = f2bf(acc0[reg]);
        poutb[base + 32] = f2bf(acc1[reg]);
    }
}

// K4: out = elu( (sum_q bf2f(poutb[q])) / (sum_q rowpart[q]) ), 4 quarters.
__global__ __launch_bounds__(256) void k4_reduce(const unsigned short* __restrict__ poutb,
                                                 const float* __restrict__ rowpart,
                                                 float* __restrict__ out) {
    int t = blockIdx.x * 256 + threadIdx.x;
    int row = t >> 8;
    float s = 0.f, l = 0.f;
#pragma unroll
    for (int q = 0; q < 4; ++q) {
        s += bf2f(poutb[(size_t)q * N_NODES * OUT_FEAT + t]);
        l += rowpart[q * N_NODES + row];
    }
    float inv = (l > 0.f) ? 1.0f / l : 0.f;
    float x = s * inv;
    out[t] = (x > 0.f) ? x : (__builtin_amdgcn_exp2f(x * LOG2E) - 1.0f);
}

extern "C" void kernel_launch(void* const* d_in, const int* in_sizes, int n_in,
                              void* d_out, int out_size, void* d_ws, size_t ws_size,
                              hipStream_t stream) {
    const float* input = (const float*)d_in[0];
    const int* adj = (const int*)d_in[1];
    const float* W = (const float*)d_in[2];
    const float* a_vec = (const float*)d_in[3];
    float* out = (float*)d_out;

    char* ws = (char*)d_ws;
    unsigned short* Wt    = (unsigned short*)(ws);               // 256 KB
    unsigned short* hTf32 = (unsigned short*)(ws + 262144);      // 4 MB
    float*  e12     = (float*)(ws + 4456448);                    // 64 KB
    float2* row2    = (float2*)(ws + 4521984);                   // 64 KB
    float*  s1_raw  = (float*)(ws + 4587520);                    // 32 KB
    float*  s2_raw  = (float*)(ws + 4620288);                    // 32 KB
    float*  rowpart = (float*)(ws + 4653056);                    // 128 KB
    unsigned short* poutb = (unsigned short*)(ws + 4915200);     // 16 MB

    hipLaunchKernelGGL(k0_transpose_w, dim3(512), dim3(256), 0, stream, W, Wt);
    hipLaunchKernelGGL(k1_hgemm, dim3(N_NODES / 64), dim3(256), 0, stream,
                       input, Wt, a_vec, hTf32, s1_raw, s2_raw);
    hipLaunchKernelGGL(k2_prep, dim3(32), dim3(256), 0, stream, s1_raw, s2_raw, e12, row2);
    hipLaunchKernelGGL(k3_flash, dim3(1024), dim3(256), 0, stream,
                       adj, hTf32, e12, row2, poutb, rowpart);
    hipLaunchKernelGGL(k4_reduce, dim3(N_NODES * OUT_FEAT / 256), dim3(256), 0, stream,
                       poutb, rowpart, out);
}

// Round 25
// 153.714 us; speedup vs baseline: 1.0034x; 1.0034x over previous
//
#include <hip/hip_runtime.h>
#include <stdint.h>

#define N_NODES 8192
#define IN_FEAT 512
#define OUT_FEAT 256
#define LOG2E 1.4426950408889634f

typedef __bf16 b16x8 __attribute__((ext_vector_type(8)));
typedef unsigned short u16x8v __attribute__((ext_vector_type(8)));
typedef float f32x4 __attribute__((ext_vector_type(4)));
typedef float f32x16 __attribute__((ext_vector_type(16)));

static __device__ __forceinline__ unsigned short f2bf(float f) {
    union { float f; uint32_t u; } v; v.f = f;
    uint32_t r = v.u + 0x7FFFu + ((v.u >> 16) & 1u);
    return (unsigned short)(r >> 16);
}
static __device__ __forceinline__ float bf2f(unsigned short s) {
    union { uint32_t u; float f; } v; v.u = ((uint32_t)s) << 16;
    return v.f;
}

// K0: Wt[c][k] = bf16(W[k][c])  (256 x 512)
__global__ __launch_bounds__(256) void k0_transpose_w(const float* __restrict__ W,
                                                      unsigned short* __restrict__ Wt) {
    int tid = blockIdx.x * 256 + threadIdx.x;
    int c = tid & (OUT_FEAT - 1);
    int k = tid >> 8;
    Wt[(size_t)c * IN_FEAT + k] = f2bf(W[(size_t)k * OUT_FEAT + c]);
}

// K1: h = X @ W via bf16 MFMA (16x16x32 internally). Writes hTf32 in the
// B-fragment order of mfma_f32_32x32x16_bf16 (verified R16).
__global__ __launch_bounds__(256) void k1_hgemm(const float* __restrict__ input,
                                                const unsigned short* __restrict__ Wt,
                                                const float* __restrict__ a_vec,
                                                unsigned short* __restrict__ hTf32,
                                                float* __restrict__ s1_raw,
                                                float* __restrict__ s2_raw) {
    int tid = threadIdx.x;
    int lane = tid & 63;
    int c = lane & 15, g = lane >> 4;
    int r0 = blockIdx.x * 64 + (tid >> 6) * 16;
    f32x4 acc[16];
#pragma unroll
    for (int t = 0; t < 16; ++t) acc[t] = (f32x4){0.f, 0.f, 0.f, 0.f};
    const float* arow = input + (size_t)(r0 + c) * IN_FEAT;
#pragma unroll 1
    for (int kk = 0; kk < IN_FEAT / 32; ++kk) {
        int kb = kk * 32 + 8 * g;
        float4 x0 = *(const float4*)(arow + kb);
        float4 x1 = *(const float4*)(arow + kb + 4);
        u16x8v au;
        au[0] = f2bf(x0.x); au[1] = f2bf(x0.y); au[2] = f2bf(x0.z); au[3] = f2bf(x0.w);
        au[4] = f2bf(x1.x); au[5] = f2bf(x1.y); au[6] = f2bf(x1.z); au[7] = f2bf(x1.w);
        b16x8 af = __builtin_bit_cast(b16x8, au);
#pragma unroll
        for (int t = 0; t < 16; ++t) {
            b16x8 bf = __builtin_bit_cast(b16x8,
                *(const u16x8v*)(Wt + (size_t)(16 * t + c) * IN_FEAT + kb));
            acc[t] = __builtin_amdgcn_mfma_f32_16x16x32_bf16(af, bf, acc[t], 0, 0, 0);
        }
    }
    float a1v[16], a2v[16];
#pragma unroll
    for (int t = 0; t < 16; ++t) {
        a1v[t] = a_vec[16 * t + c];
        a2v[t] = a_vec[OUT_FEAT + 16 * t + c];
    }
#pragma unroll
    for (int r = 0; r < 4; ++r) {
        float s1p = 0.f, s2p = 0.f;
#pragma unroll
        for (int t = 0; t < 16; ++t) { s1p += acc[t][r] * a1v[t]; s2p += acc[t][r] * a2v[t]; }
#pragma unroll
        for (int m = 1; m <= 8; m <<= 1) { s1p += __shfl_xor(s1p, m); s2p += __shfl_xor(s2p, m); }
        if (c == 0) {
            int row = r0 + 4 * g + r;
            s1_raw[row] = s1p;
            s2_raw[row] = s2p;
        }
    }
    // store in 32x32 B-frag order
    int chunk16 = r0 >> 4;
    int lane_base = c + 32 * (g >> 1);
    int e0 = 4 * (g & 1);
#pragma unroll
    for (int t = 0; t < 16; ++t) {
        ushort4 pk;
        pk.x = f2bf(acc[t][0]); pk.y = f2bf(acc[t][1]);
        pk.z = f2bf(acc[t][2]); pk.w = f2bf(acc[t][3]);
        int lane_t = 16 * (t & 1) + lane_base;
        *(ushort4*)(hTf32 + ((size_t)(chunk16 * 8 + (t >> 1)) * 64 + lane_t) * 8 + e0) = pk;
    }
}

// K2: factored-exp constants.
__global__ __launch_bounds__(256) void k2_prep(const float* __restrict__ s1_raw,
                                               const float* __restrict__ s2_raw,
                                               float* __restrict__ e12,
                                               float2* __restrict__ row2) {
    __shared__ float red[256];
    int tid = threadIdx.x;
    float m = -3.0e38f;
    for (int j = tid; j < N_NODES; j += 256) m = fmaxf(m, s2_raw[j]);
    red[tid] = m;
    __syncthreads();
    for (int s = 128; s > 0; s >>= 1) {
        if (tid < s) red[tid] = fmaxf(red[tid], red[tid + s]);
        __syncthreads();
    }
    float M2 = red[0];
    int i = blockIdx.x * 256 + tid;
    float s1 = s1_raw[i];
    float u = s1 + M2;
    float mi = fmaxf(u, 0.2f * u);                 // per-row upper bound on e
    row2[i] = make_float2(__builtin_amdgcn_exp2f((s1 - mi) * LOG2E),
                          __builtin_amdgcn_exp2f((0.2f * s1 - mi) * LOG2E));
    float s2 = s2_raw[i];
    e12[2 * i]     = __builtin_amdgcn_exp2f(s2 * LOG2E);
    e12[2 * i + 1] = __builtin_amdgcn_exp2f(0.2f * s2 * LOG2E);
}

// K3 v24: R23 config (jq=8, grid 2048, 2x oversubscription) + DEPTH-2 adj
// register pipeline. Iteration kc8 (0..7):
//   A) issue adj loads for group kc8+2 -> vb
//   B) produce 2 af slots from lmask[cur]
//   barrier
//   C) consume 8 slots (b-frags + 16 MFMA)
//   D) pack va (group kc8+1, issued LAST iteration: ~1.7 phases ~1100cy of
//      latency cover > HBM ~900cy) -> lmask[cur^1]; va = vb
//   barrier
__global__ __launch_bounds__(256, 4) void k3_flash(const int* __restrict__ adj,
                                                   const unsigned short* __restrict__ hTf32,
                                                   const float* __restrict__ e12g,
                                                   const float2* __restrict__ row2,
                                                   unsigned short* __restrict__ poutb,
                                                   float* __restrict__ rowpart) {
    __shared__ __align__(16) float le12[2048];               // 8 KB (eighth)
    __shared__ __align__(16) unsigned short laf[8][512];     // 8 KB af slots
    __shared__ __align__(16) uint32_t lmask[2][32][4];       // 1 KB dbuf masks
    __shared__ float lsum[4][64];                            // 1 KB

    int tid = threadIdx.x;
    int cq = tid >> 6, lane = tid & 63;
    int lr = lane & 31, lo = lane >> 5;
    int jq = blockIdx.x & 7;
    int rg = blockIdx.x >> 3;
    int rowbase = rg * 32;

    // adj staging mapping: thread t -> row t>>3, j-block (t&7)*16 within group
    int srow = tid >> 3;
    int sjb = tid & 7;
    const int* adjbase = adj + (size_t)(rowbase + srow) * N_NODES + jq * 1024 + sjb * 16;

    // ---- prologue: stage e12 eighth (8 floats/thread) ----
    *(float4*)&le12[tid * 8]     = *(const float4*)(e12g + (size_t)jq * 2048 + tid * 8);
    *(float4*)&le12[tid * 8 + 4] = *(const float4*)(e12g + (size_t)jq * 2048 + tid * 8 + 4);

#define PACK16(BUF, V)                                                                   \
    {                                                                                    \
        unsigned pb = 0;                                                                 \
        _Pragma("unroll")                                                                \
        for (int k = 0; k < 4; ++k) {                                                    \
            pb |= ((unsigned)((V)[k].x != 0) << (4 * k))                                 \
                | ((unsigned)((V)[k].y != 0) << (4 * k + 1))                             \
                | ((unsigned)((V)[k].z != 0) << (4 * k + 2))                             \
                | ((unsigned)((V)[k].w != 0) << (4 * k + 3));                            \
        }                                                                                \
        *(unsigned short*)((char*)&lmask[BUF][srow][0] + sjb * 2) = (unsigned short)pb;  \
    }

    {   // synchronous pack of group 0 into lmask[0]
        int4 v[4];
#pragma unroll
        for (int k = 0; k < 4; ++k) v[k] = *(const int4*)(adjbase + 4 * k);
        PACK16(0, v)
    }
    // in-flight regs for group 1 (packed at D of kc8=0)
    int4 va0 = *(const int4*)(adjbase + 128);
    int4 va1 = *(const int4*)(adjbase + 132);
    int4 va2 = *(const int4*)(adjbase + 136);
    int4 va3 = *(const int4*)(adjbase + 140);
    float2 rc = row2[rowbase + lr];
    float E1r = rc.x, E2r = rc.y;
    __syncthreads();

    f32x16 acc0 = {0}, acc1 = {0};
    float lacc = 0.f;

#pragma unroll 1
    for (int kc8 = 0; kc8 < 8; ++kc8) {
        int cur = kc8 & 1;

        // A) issue adj loads for group kc8+2 (packed NEXT iteration)
        int4 vb0, vb1, vb2, vb3;
        if (kc8 < 6) {
            vb0 = *(const int4*)(adjbase + (kc8 + 2) * 128);
            vb1 = *(const int4*)(adjbase + (kc8 + 2) * 128 + 4);
            vb2 = *(const int4*)(adjbase + (kc8 + 2) * 128 + 8);
            vb3 = *(const int4*)(adjbase + (kc8 + 2) * 128 + 12);
        }

        // B) produce 2 af slots (chunks kc8*8+cq, kc8*8+4+cq) from lmask[cur]
        int4 mq = *(const int4*)&lmask[cur][lr][0];
        uint32_t md[4] = {(uint32_t)mq.x, (uint32_t)mq.y, (uint32_t)mq.z, (uint32_t)mq.w};
#pragma unroll
        for (int hh = 0; hh < 2; ++hh) {
            int sl = hh * 4 + cq;
            int kc = kc8 * 8 + sl;                 // chunk16 in eighth (0..63)
            float ev[16];
#pragma unroll
            for (int q = 0; q < 4; ++q)
                *(f32x4*)&ev[q * 4] = *(const f32x4*)&le12[(kc * 16 + 8 * lo) * 2 + q * 4];
            uint32_t mb = (md[sl >> 1] >> (16 * (sl & 1) + 8 * lo)) & 0xFFu;
            b16x8 af;
#pragma unroll
            for (int e = 0; e < 8; ++e) {
                float q0 = fmaxf(E1r * ev[2 * e], E2r * ev[2 * e + 1]);
                float p = (mb & (1u << e)) ? q0 : 0.f;
                lacc += p;
                af[e] = (__bf16)p;
            }
            *(u16x8v*)&laf[sl][lane * 8] = __builtin_bit_cast(u16x8v, af);
        }
        __syncthreads();

        // C) consume 8 slots with this wave's 2 col-tiles
        int gchunk0 = jq * 64 + kc8 * 8;           // global chunk16
#pragma unroll
        for (int s = 0; s < 8; ++s) {
            const unsigned short* tb =
                hTf32 + ((size_t)((gchunk0 + s) * 8 + 2 * cq) * 64 + lane) * 8;
            b16x8 bf0 = __builtin_bit_cast(b16x8, *(const u16x8v*)(tb));
            b16x8 bf1 = __builtin_bit_cast(b16x8, *(const u16x8v*)(tb + 512));
            b16x8 afs = __builtin_bit_cast(b16x8, *(const u16x8v*)&laf[s][lane * 8]);
            acc0 = __builtin_amdgcn_mfma_f32_32x32x16_bf16(afs, bf0, acc0, 0, 0, 0);
            acc1 = __builtin_amdgcn_mfma_f32_32x32x16_bf16(afs, bf1, acc1, 0, 0, 0);
        }

        // D) pack group kc8+1 (regs from last iteration; counted vmcnt); rotate
        if (kc8 < 7) {
            int4 va[4] = {va0, va1, va2, va3};
            PACK16(cur ^ 1, va)
        }
        va0 = vb0; va1 = vb1; va2 = vb2; va3 = vb3;
        __syncthreads();                           // laf + lmask[cur^1] ready
    }
#undef PACK16

    // row sums: wave cq produced chunks ≡ {cq, cq+4} (mod 8); merge via LDS
    lsum[cq][lane] = lacc;
    __syncthreads();
    if (cq == 0) {
        float l = lsum[0][lane] + lsum[1][lane] + lsum[2][lane] + lsum[3][lane];
        float ltot = l + __shfl_xor(l, 32);
        if (lo == 0) rowpart[jq * N_NODES + rowbase + lr] = ltot;
    }

    // C layout (32x32): col = lane&31, row = (reg&3) + 8*(reg>>2) + 4*(lane>>5)
#pragma unroll
    for (int reg = 0; reg < 16; ++reg) {
        int row = (reg & 3) + 8 * (reg >> 2) + 4 * lo;
        size_t base = ((size_t)jq * N_NODES + rowbase + row) * OUT_FEAT + cq * 64 + lr;
        poutb[base] = f2bf(acc0[reg]);
        poutb[base + 32] = f2bf(acc1[reg]);
    }
}

// K4: out = elu( (sum_q bf2f(poutb[q])) / (sum_q rowpart[q]) ), 8 eighths.
__global__ __launch_bounds__(256) void k4_reduce(const unsigned short* __restrict__ poutb,
                                                 const float* __restrict__ rowpart,
                                                 float* __restrict__ out) {
    int t = blockIdx.x * 256 + threadIdx.x;
    int row = t >> 8;
    float s = 0.f, l = 0.f;
#pragma unroll
    for (int q = 0; q < 8; ++q) {
        s += bf2f(poutb[(size_t)q * N_NODES * OUT_FEAT + t]);
        l += rowpart[q * N_NODES + row];
    }
    float inv = (l > 0.f) ? 1.0f / l : 0.f;
    float x = s * inv;
    out[t] = (x > 0.f) ? x : (__builtin_amdgcn_exp2f(x * LOG2E) - 1.0f);
}

extern "C" void kernel_launch(void* const* d_in, const int* in_sizes, int n_in,
                              void* d_out, int out_size, void* d_ws, size_t ws_size,
                              hipStream_t stream) {
    const float* input = (const float*)d_in[0];
    const int* adj = (const int*)d_in[1];
    const float* W = (const float*)d_in[2];
    const float* a_vec = (const float*)d_in[3];
    float* out = (float*)d_out;

    char* ws = (char*)d_ws;
    unsigned short* Wt    = (unsigned short*)(ws);               // 256 KB
    unsigned short* hTf32 = (unsigned short*)(ws + 262144);      // 4 MB
    float*  e12     = (float*)(ws + 4456448);                    // 64 KB
    float2* row2    = (float2*)(ws + 4521984);                   // 64 KB
    float*  s1_raw  = (float*)(ws + 4587520);                    // 32 KB
    float*  s2_raw  = (float*)(ws + 4620288);                    // 32 KB
    float*  rowpart = (float*)(ws + 4653056);                    // 256 KB
    unsigned short* poutb = (unsigned short*)(ws + 4915200);     // 32 MB

    hipLaunchKernelGGL(k0_transpose_w, dim3(512), dim3(256), 0, stream, W, Wt);
    hipLaunchKernelGGL(k1_hgemm, dim3(N_NODES / 64), dim3(256), 0, stream,
                       input, Wt, a_vec, hTf32, s1_raw, s2_raw);
    hipLaunchKernelGGL(k2_prep, dim3(32), dim3(256), 0, stream, s1_raw, s2_raw, e12, row2);
    hipLaunchKernelGGL(k3_flash, dim3(2048), dim3(256), 0, stream,
                       adj, hTf32, e12, row2, poutb, rowpart);
    hipLaunchKernelGGL(k4_reduce, dim3(N_NODES * OUT_FEAT / 256), dim3(256), 0, stream,
                       poutb, rowpart, out);
}

// Round 26
// 146.618 us; speedup vs baseline: 1.0520x; 1.0484x over previous
//
#include <hip/hip_runtime.h>
#include <stdint.h>

#define N_NODES 8192
#define IN_FEAT 512
#define OUT_FEAT 256
#define LOG2E 1.4426950408889634f

typedef __bf16 b16x8 __attribute__((ext_vector_type(8)));
typedef unsigned short u16x8v __attribute__((ext_vector_type(8)));
typedef float f32x4 __attribute__((ext_vector_type(4)));
typedef float f32x16 __attribute__((ext_vector_type(16)));

static __device__ __forceinline__ unsigned short f2bf(float f) {
    union { float f; uint32_t u; } v; v.f = f;
    uint32_t r = v.u + 0x7FFFu + ((v.u >> 16) & 1u);
    return (unsigned short)(r >> 16);
}
static __device__ __forceinline__ float bf2f(unsigned short s) {
    union { uint32_t u; float f; } v; v.u = ((uint32_t)s) << 16;
    return v.f;
}

// K0: Wt[c][k] = bf16(W[k][c])  (256 x 512)
__global__ __launch_bounds__(256) void k0_transpose_w(const float* __restrict__ W,
                                                      unsigned short* __restrict__ Wt) {
    int tid = blockIdx.x * 256 + threadIdx.x;
    int c = tid & (OUT_FEAT - 1);
    int k = tid >> 8;
    Wt[(size_t)c * IN_FEAT + k] = f2bf(W[(size_t)k * OUT_FEAT + c]);
}

// K1: h = X @ W via bf16 MFMA (16x16x32 internally). Writes hTf32 in the
// B-fragment order of mfma_f32_32x32x16_bf16 (verified R16).
__global__ __launch_bounds__(256) void k1_hgemm(const float* __restrict__ input,
                                                const unsigned short* __restrict__ Wt,
                                                const float* __restrict__ a_vec,
                                                unsigned short* __restrict__ hTf32,
                                                float* __restrict__ s1_raw,
                                                float* __restrict__ s2_raw) {
    int tid = threadIdx.x;
    int lane = tid & 63;
    int c = lane & 15, g = lane >> 4;
    int r0 = blockIdx.x * 64 + (tid >> 6) * 16;
    f32x4 acc[16];
#pragma unroll
    for (int t = 0; t < 16; ++t) acc[t] = (f32x4){0.f, 0.f, 0.f, 0.f};
    const float* arow = input + (size_t)(r0 + c) * IN_FEAT;
#pragma unroll 1
    for (int kk = 0; kk < IN_FEAT / 32; ++kk) {
        int kb = kk * 32 + 8 * g;
        float4 x0 = *(const float4*)(arow + kb);
        float4 x1 = *(const float4*)(arow + kb + 4);
        u16x8v au;
        au[0] = f2bf(x0.x); au[1] = f2bf(x0.y); au[2] = f2bf(x0.z); au[3] = f2bf(x0.w);
        au[4] = f2bf(x1.x); au[5] = f2bf(x1.y); au[6] = f2bf(x1.z); au[7] = f2bf(x1.w);
        b16x8 af = __builtin_bit_cast(b16x8, au);
#pragma unroll
        for (int t = 0; t < 16; ++t) {
            b16x8 bf = __builtin_bit_cast(b16x8,
                *(const u16x8v*)(Wt + (size_t)(16 * t + c) * IN_FEAT + kb));
            acc[t] = __builtin_amdgcn_mfma_f32_16x16x32_bf16(af, bf, acc[t], 0, 0, 0);
        }
    }
    float a1v[16], a2v[16];
#pragma unroll
    for (int t = 0; t < 16; ++t) {
        a1v[t] = a_vec[16 * t + c];
        a2v[t] = a_vec[OUT_FEAT + 16 * t + c];
    }
#pragma unroll
    for (int r = 0; r < 4; ++r) {
        float s1p = 0.f, s2p = 0.f;
#pragma unroll
        for (int t = 0; t < 16; ++t) { s1p += acc[t][r] * a1v[t]; s2p += acc[t][r] * a2v[t]; }
#pragma unroll
        for (int m = 1; m <= 8; m <<= 1) { s1p += __shfl_xor(s1p, m); s2p += __shfl_xor(s2p, m); }
        if (c == 0) {
            int row = r0 + 4 * g + r;
            s1_raw[row] = s1p;
            s2_raw[row] = s2p;
        }
    }
    // store in 32x32 B-frag order
    int chunk16 = r0 >> 4;
    int lane_base = c + 32 * (g >> 1);
    int e0 = 4 * (g & 1);
#pragma unroll
    for (int t = 0; t < 16; ++t) {
        ushort4 pk;
        pk.x = f2bf(acc[t][0]); pk.y = f2bf(acc[t][1]);
        pk.z = f2bf(acc[t][2]); pk.w = f2bf(acc[t][3]);
        int lane_t = 16 * (t & 1) + lane_base;
        *(ushort4*)(hTf32 + ((size_t)(chunk16 * 8 + (t >> 1)) * 64 + lane_t) * 8 + e0) = pk;
    }
}

// K2: factored-exp constants.
__global__ __launch_bounds__(256) void k2_prep(const float* __restrict__ s1_raw,
                                               const float* __restrict__ s2_raw,
                                               float* __restrict__ e12,
                                               float2* __restrict__ row2) {
    __shared__ float red[256];
    int tid = threadIdx.x;
    float m = -3.0e38f;
    for (int j = tid; j < N_NODES; j += 256) m = fmaxf(m, s2_raw[j]);
    red[tid] = m;
    __syncthreads();
    for (int s = 128; s > 0; s >>= 1) {
        if (tid < s) red[tid] = fmaxf(red[tid], red[tid + s]);
        __syncthreads();
    }
    float M2 = red[0];
    int i = blockIdx.x * 256 + tid;
    float s1 = s1_raw[i];
    float u = s1 + M2;
    float mi = fmaxf(u, 0.2f * u);                 // per-row upper bound on e
    row2[i] = make_float2(__builtin_amdgcn_exp2f((s1 - mi) * LOG2E),
                          __builtin_amdgcn_exp2f((0.2f * s1 - mi) * LOG2E));
    float s2 = s2_raw[i];
    e12[2 * i]     = __builtin_amdgcn_exp2f(s2 * LOG2E);
    e12[2 * i + 1] = __builtin_amdgcn_exp2f(0.2f * s2 * LOG2E);
}

// K3 v25: R23 (depth-1 in-loop adj pipeline, jq=8) + PHASE-STAGGERED group
// order. Each block processes its 8 j-groups in rotated order starting at
// (rg & 7) — accumulation is order-independent. Co-resident blocks (same jq,
// different rg) thus sit at DIFFERENT pipeline phases: one block's produce
// (VALU/LDS) overlaps another's consume (MFMA/L1) and adj bursts spread out
// in time, breaking the convoy effect that made dbuf/setprio/depth-2 neutral.
__global__ __launch_bounds__(256, 4) void k3_flash(const int* __restrict__ adj,
                                                   const unsigned short* __restrict__ hTf32,
                                                   const float* __restrict__ e12g,
                                                   const float2* __restrict__ row2,
                                                   unsigned short* __restrict__ poutb,
                                                   float* __restrict__ rowpart) {
    __shared__ __align__(16) float le12[2048];               // 8 KB (eighth)
    __shared__ __align__(16) unsigned short laf[8][512];     // 8 KB af slots
    __shared__ __align__(16) uint32_t lmask[2][32][4];       // 1 KB dbuf masks
    __shared__ float lsum[4][64];                            // 1 KB

    int tid = threadIdx.x;
    int cq = tid >> 6, lane = tid & 63;
    int lr = lane & 31, lo = lane >> 5;
    int jq = blockIdx.x & 7;
    int rg = blockIdx.x >> 3;
    int rowbase = rg * 32;
    int start = rg & 7;                  // per-block phase offset

    // adj staging mapping: thread t -> row t>>3, j-block (t&7)*16 within group
    int srow = tid >> 3;
    int sjb = tid & 7;
    const int* adjbase = adj + (size_t)(rowbase + srow) * N_NODES + jq * 1024 + sjb * 16;

    // ---- prologue: stage e12 eighth (8 floats/thread) ----
    *(float4*)&le12[tid * 8]     = *(const float4*)(e12g + (size_t)jq * 2048 + tid * 8);
    *(float4*)&le12[tid * 8 + 4] = *(const float4*)(e12g + (size_t)jq * 2048 + tid * 8 + 4);

#define PACK16(BUF, V)                                                                   \
    {                                                                                    \
        unsigned pb = 0;                                                                 \
        _Pragma("unroll")                                                                \
        for (int k = 0; k < 4; ++k) {                                                    \
            pb |= ((unsigned)((V)[k].x != 0) << (4 * k))                                 \
                | ((unsigned)((V)[k].y != 0) << (4 * k + 1))                             \
                | ((unsigned)((V)[k].z != 0) << (4 * k + 2))                             \
                | ((unsigned)((V)[k].w != 0) << (4 * k + 3));                            \
        }                                                                                \
        *(unsigned short*)((char*)&lmask[BUF][srow][0] + sjb * 2) = (unsigned short)pb;  \
    }

    {   // synchronous pack of group `start` into lmask[0]
        int4 v[4];
#pragma unroll
        for (int k = 0; k < 4; ++k) v[k] = *(const int4*)(adjbase + start * 128 + 4 * k);
        PACK16(0, v)
    }
    float2 rc = row2[rowbase + lr];
    float E1r = rc.x, E2r = rc.y;
    __syncthreads();

    f32x16 acc0 = {0}, acc1 = {0};
    float lacc = 0.f;

#pragma unroll 1
    for (int i = 0; i < 8; ++i) {
        int cur = i & 1;
        int gci = (start + i) & 7;                 // group processed this iteration
        int gni = (start + i + 1) & 7;             // group staged this iteration

        // A) issue adj loads for next group (packed at D, ~1 phase later)
        int4 v[4];
        if (i < 7) {
#pragma unroll
            for (int k = 0; k < 4; ++k)
                v[k] = *(const int4*)(adjbase + gni * 128 + 4 * k);
        }

        // B) produce 2 af slots (chunks gci*8+cq, gci*8+4+cq) from lmask[cur]
        int4 mq = *(const int4*)&lmask[cur][lr][0];
        uint32_t md[4] = {(uint32_t)mq.x, (uint32_t)mq.y, (uint32_t)mq.z, (uint32_t)mq.w};
#pragma unroll
        for (int hh = 0; hh < 2; ++hh) {
            int sl = hh * 4 + cq;
            int kc = gci * 8 + sl;                 // chunk16 in eighth (0..63)
            float ev[16];
#pragma unroll
            for (int q = 0; q < 4; ++q)
                *(f32x4*)&ev[q * 4] = *(const f32x4*)&le12[(kc * 16 + 8 * lo) * 2 + q * 4];
            uint32_t mb = (md[sl >> 1] >> (16 * (sl & 1) + 8 * lo)) & 0xFFu;
            b16x8 af;
#pragma unroll
            for (int e = 0; e < 8; ++e) {
                float q0 = fmaxf(E1r * ev[2 * e], E2r * ev[2 * e + 1]);
                float p = (mb & (1u << e)) ? q0 : 0.f;
                lacc += p;
                af[e] = (__bf16)p;
            }
            *(u16x8v*)&laf[sl][lane * 8] = __builtin_bit_cast(u16x8v, af);
        }
        __syncthreads();

        // C) consume 8 slots with this wave's 2 col-tiles
        int gchunk0 = jq * 64 + gci * 8;           // global chunk16
#pragma unroll
        for (int s = 0; s < 8; ++s) {
            const unsigned short* tb =
                hTf32 + ((size_t)((gchunk0 + s) * 8 + 2 * cq) * 64 + lane) * 8;
            b16x8 bf0 = __builtin_bit_cast(b16x8, *(const u16x8v*)(tb));
            b16x8 bf1 = __builtin_bit_cast(b16x8, *(const u16x8v*)(tb + 512));
            b16x8 afs = __builtin_bit_cast(b16x8, *(const u16x8v*)&laf[s][lane * 8]);
            acc0 = __builtin_amdgcn_mfma_f32_32x32x16_bf16(afs, bf0, acc0, 0, 0, 0);
            acc1 = __builtin_amdgcn_mfma_f32_32x32x16_bf16(afs, bf1, acc1, 0, 0, 0);
        }

        // D) pack next group (regs waited here, counted vmcnt)
        if (i < 7) PACK16(cur ^ 1, v)
        __syncthreads();                           // laf + lmask[cur^1] ready
    }
#undef PACK16

    // row sums: wave cq produced chunks ≡ {cq, cq+4} (mod 8); merge via LDS
    lsum[cq][lane] = lacc;
    __syncthreads();
    if (cq == 0) {
        float l = lsum[0][lane] + lsum[1][lane] + lsum[2][lane] + lsum[3][lane];
        float ltot = l + __shfl_xor(l, 32);
        if (lo == 0) rowpart[jq * N_NODES + rowbase + lr] = ltot;
    }

    // C layout (32x32): col = lane&31, row = (reg&3) + 8*(reg>>2) + 4*(lane>>5)
#pragma unroll
    for (int reg = 0; reg < 16; ++reg) {
        int row = (reg & 3) + 8 * (reg >> 2) + 4 * lo;
        size_t base = ((size_t)jq * N_NODES + rowbase + row) * OUT_FEAT + cq * 64 + lr;
        poutb[base] = f2bf(acc0[reg]);
        poutb[base + 32] = f2bf(acc1[reg]);
    }
}

// K4: out = elu( (sum_q bf2f(poutb[q])) / (sum_q rowpart[q]) ), 8 eighths.
__global__ __launch_bounds__(256) void k4_reduce(const unsigned short* __restrict__ poutb,
                                                 const float* __restrict__ rowpart,
                                                 float* __restrict__ out) {
    int t = blockIdx.x * 256 + threadIdx.x;
    int row = t >> 8;
    float s = 0.f, l = 0.f;
#pragma unroll
    for (int q = 0; q < 8; ++q) {
        s += bf2f(poutb[(size_t)q * N_NODES * OUT_FEAT + t]);
        l += rowpart[q * N_NODES + row];
    }
    float inv = (l > 0.f) ? 1.0f / l : 0.f;
    float x = s * inv;
    out[t] = (x > 0.f) ? x : (__builtin_amdgcn_exp2f(x * LOG2E) - 1.0f);
}

extern "C" void kernel_launch(void* const* d_in, const int* in_sizes, int n_in,
                              void* d_out, int out_size, void* d_ws, size_t ws_size,
                              hipStream_t stream) {
    const float* input = (const float*)d_in[0];
    const int* adj = (const int*)d_in[1];
    const float* W = (const float*)d_in[2];
    const float* a_vec = (const float*)d_in[3];
    float* out = (float*)d_out;

    char* ws = (char*)d_ws;
    unsigned short* Wt    = (unsigned short*)(ws);               // 256 KB
    unsigned short* hTf32 = (unsigned short*)(ws + 262144);      // 4 MB
    float*  e12     = (float*)(ws + 4456448);                    // 64 KB
    float2* row2    = (float2*)(ws + 4521984);                   // 64 KB
    float*  s1_raw  = (float*)(ws + 4587520);                    // 32 KB
    float*  s2_raw  = (float*)(ws + 4620288);                    // 32 KB
    float*  rowpart = (float*)(ws + 4653056);                    // 256 KB
    unsigned short* poutb = (unsigned short*)(ws + 4915200);     // 32 MB

    hipLaunchKernelGGL(k0_transpose_w, dim3(512), dim3(256), 0, stream, W, Wt);
    hipLaunchKernelGGL(k1_hgemm, dim3(N_NODES / 64), dim3(256), 0, stream,
                       input, Wt, a_vec, hTf32, s1_raw, s2_raw);
    hipLaunchKernelGGL(k2_prep, dim3(32), dim3(256), 0, stream, s1_raw, s2_raw, e12, row2);
    hipLaunchKernelGGL(k3_flash, dim3(2048), dim3(256), 0, stream,
                       adj, hTf32, e12, row2, poutb, rowpart);
    hipLaunchKernelGGL(k4_reduce, dim3(N_NODES * OUT_FEAT / 256), dim3(256), 0, stream,
                       poutb, rowpart, out);
}